// Round 10
// baseline (335.520 us; speedup 1.0000x reference)
//
#include <hip/hip_runtime.h>
#include <hip/hip_bf16.h>
#include <stdint.h>

#define S_LEN   2048
#define DIN     2048
#define NHEADS  32
#define HDIM    64
#define NKV     8

typedef __bf16 bf16x8 __attribute__((ext_vector_type(8)));
typedef float  f32x4  __attribute__((ext_vector_type(4)));

#define AS1(p) ((__attribute__((address_space(1))) void*)(void*)(p))
#define AS3(p) ((__attribute__((address_space(3))) void*)(p))
#define MFMA_BF16 __builtin_amdgcn_mfma_f32_16x16x32_bf16

#if __has_builtin(__builtin_amdgcn_exp2f)
#define EXP2F(x) __builtin_amdgcn_exp2f(x)
#else
#define EXP2F(x) exp2f(x)
#endif

static __device__ __forceinline__ unsigned short f2bf(float f) {
  unsigned int x = __float_as_uint(f);
  return (unsigned short)((x + 0x7fffu + ((x >> 16) & 1u)) >> 16);
}
static __device__ __forceinline__ float bf2f(unsigned short u) {
  return __uint_as_float((unsigned int)u << 16);
}

// ---------------- fused prep: cast x + transpose Wqkv + transpose Wo ----------------
__global__ __launch_bounds__(256) void prep_kernel(const float* __restrict__ x,
                                                   const float* __restrict__ Wq,
                                                   const float* __restrict__ Wk,
                                                   const float* __restrict__ Wv,
                                                   const float* __restrict__ Wo,
                                                   unsigned short* __restrict__ xb,
                                                   unsigned short* __restrict__ wcat,
                                                   unsigned short* __restrict__ wo_t) {
  const int bid = blockIdx.x;
  if (bid < 8192) {                      // cast x: 8192*256 == 2097152 float4s exactly
    int i = bid * 256 + threadIdx.x;
    float4 f = ((const float4*)x)[i];
    ((ushort4*)xb)[i] = make_ushort4(f2bf(f.x), f2bf(f.y), f2bf(f.z), f2bf(f.w));
    return;
  }
  __shared__ float t[32][33];
  const int tx = threadIdx.x & 31, ty = threadIdx.x >> 5;
  const float* src; unsigned short* dst; int n0, k0, col0, srcN, dstK;
  if (bid < 14336) {                     // Wqkv transpose: grid (96,64)
    int b2 = bid - 8192;
    n0 = (b2 % 96) * 32; k0 = (b2 / 96) * 32;
    if (n0 < 2048)      { src = Wq; col0 = n0;        srcN = 2048; }
    else if (n0 < 2560) { src = Wk; col0 = n0 - 2048; srcN = 512; }
    else                { src = Wv; col0 = n0 - 2560; srcN = 512; }
    dst = wcat; dstK = 2048;
  } else {                               // Wo transpose: grid (64,64)
    int b3 = bid - 14336;
    n0 = (b3 % 64) * 32; k0 = (b3 / 64) * 32;
    src = Wo; col0 = n0; srcN = 2048; dst = wo_t; dstK = 2048;
  }
  #pragma unroll
  for (int j = 0; j < 32; j += 8)
    t[ty + j][tx] = src[(size_t)(k0 + ty + j) * srcN + col0 + tx];
  __syncthreads();
  #pragma unroll
  for (int j = 0; j < 32; j += 8)
    dst[(size_t)(n0 + ty + j) * dstK + k0 + tx] = f2bf(t[tx][ty + j]);
}

// ---------------- bf16 NT GEMM, BK=64 + XCD-aware block swizzle ----------------
// Round-9 verified BK=64 structure (65.7us QKV, 0 conflicts, MfmaUtil 32) plus
// T1: 1D grid with bijective XCD remap (nwg%8==0 for both call sites). Block
// id&7 = XCD; giving each XCD a contiguous logical chunk makes consecutive
// same-XCD blocks share the A row-panel in that XCD's private L2 (FETCH was
// 72MB vs 28MB ideal = L2-fill refetch).
template <typename OutT>
__global__ __launch_bounds__(256) void gemm_nt(const unsigned short* __restrict__ A,
                                               const unsigned short* __restrict__ Bt,
                                               OutT* __restrict__ C,
                                               int M, int N, int K, int nxb) {
  __shared__ alignas(16) unsigned short As[2][4096];   // [half][128 rows x 32 k]
  __shared__ alignas(16) unsigned short Bs[2][4096];
  const int tid = threadIdx.x;
  const int wave = tid >> 6, lane = tid & 63;
  const int g = lane >> 4, c = lane & 15;
  const int id = blockIdx.x;
  const int cpx = gridDim.x >> 3;                      // blocks per XCD
  const int swb = (id & 7) * cpx + (id >> 3);          // bijective XCD chunking
  const int m0 = (swb / nxb) * 128, n0 = (swb % nxb) * 128;
  const int wm = (wave & 1) * 64, wn = (wave >> 1) * 64;

  f32x4 acc[4][4] = {};

  const int ch0 = wave * 2;
  const int p0 = ch0 * 64 + lane, p1 = p0 + 64;
  const int r0 = p0 >> 2, gc0 = ((p0 & 3) ^ ((r0 >> 1) & 3)) * 8;
  const int r1 = p1 >> 2, gc1 = ((p1 & 3) ^ ((r1 >> 1) & 3)) * 8;
  const unsigned short* a0 = A + (size_t)(m0 + r0) * K + gc0;
  const unsigned short* a1 = A + (size_t)(m0 + r1) * K + gc1;
  const unsigned short* b0 = Bt + (size_t)(n0 + r0) * K + gc0;
  const unsigned short* b1 = Bt + (size_t)(n0 + r1) * K + gc1;
  const int fswz = (c >> 1) & 3;   // f(row) for consumer rows (wm,i*16 are mult of 16)

  for (int k0 = 0; k0 < K; k0 += 64) {
    __syncthreads();
    __builtin_amdgcn_global_load_lds(AS1(a0 + k0), AS3(&As[0][ch0 * 512]), 16, 0, 0);
    __builtin_amdgcn_global_load_lds(AS1(a1 + k0), AS3(&As[0][ch0 * 512 + 512]), 16, 0, 0);
    __builtin_amdgcn_global_load_lds(AS1(b0 + k0), AS3(&Bs[0][ch0 * 512]), 16, 0, 0);
    __builtin_amdgcn_global_load_lds(AS1(b1 + k0), AS3(&Bs[0][ch0 * 512 + 512]), 16, 0, 0);
    __builtin_amdgcn_global_load_lds(AS1(a0 + k0 + 32), AS3(&As[1][ch0 * 512]), 16, 0, 0);
    __builtin_amdgcn_global_load_lds(AS1(a1 + k0 + 32), AS3(&As[1][ch0 * 512 + 512]), 16, 0, 0);
    __builtin_amdgcn_global_load_lds(AS1(b0 + k0 + 32), AS3(&Bs[1][ch0 * 512]), 16, 0, 0);
    __builtin_amdgcn_global_load_lds(AS1(b1 + k0 + 32), AS3(&Bs[1][ch0 * 512 + 512]), 16, 0, 0);
    __builtin_amdgcn_s_waitcnt(0);
    __syncthreads();

    #pragma unroll
    for (int h = 0; h < 2; h++) {
      bf16x8 af[4], bfr[4];
      #pragma unroll
      for (int i = 0; i < 4; i++)
        af[i] = *(const bf16x8*)(&As[h][(wm + i * 16 + c) * 32 + (g ^ fswz) * 8]);
      #pragma unroll
      for (int j = 0; j < 4; j++)
        bfr[j] = *(const bf16x8*)(&Bs[h][(wn + j * 16 + c) * 32 + (g ^ fswz) * 8]);
      #pragma unroll
      for (int i = 0; i < 4; i++)
        #pragma unroll
        for (int j = 0; j < 4; j++)
          acc[i][j] = MFMA_BF16(af[i], bfr[j], acc[i][j], 0, 0, 0);
    }
  }

  #pragma unroll
  for (int i = 0; i < 4; i++)
    #pragma unroll
    for (int j = 0; j < 4; j++)
      #pragma unroll
      for (int r = 0; r < 4; r++) {
        size_t idx = (size_t)(m0 + wm + i * 16 + g * 4 + r) * N + n0 + wn + j * 16 + c;
        if constexpr (sizeof(OutT) == 2) C[idx] = f2bf(acc[i][j][r]);
        else                             C[idx] = acc[i][j][r];
      }
}

// ---------------- fused norm_rope + v_transpose ----------------
__global__ __launch_bounds__(256) void norm_rope_vt(const unsigned short* __restrict__ QKV,
                                                    const float* __restrict__ cosb,
                                                    const float* __restrict__ sinb,
                                                    const float* __restrict__ q_scale,
                                                    const float* __restrict__ k_scale,
                                                    unsigned short* __restrict__ Qn,
                                                    unsigned short* __restrict__ Kn,
                                                    unsigned short* __restrict__ Vt) {
  const int tid = threadIdx.x;
  if (blockIdx.x >= 10240) {             // ---- V transpose part ----
    __shared__ unsigned int t[64][65];
    int bid = blockIdx.x - 10240;
    const int st = bid & 31, kv = (bid >> 5) & 7, b = bid >> 8;
    const int lane = tid & 63, quad = tid >> 6;
    #pragma unroll
    for (int p = 0; p < 16; p++) {
      int sl = p * 4 + quad;
      t[sl][lane] = QKV[(size_t)(b * 2048 + st * 64 + sl) * 3072 + 2560 + kv * 64 + lane];
    }
    __syncthreads();
    size_t base = (size_t)(b * 8 + kv) * 64 * 2048;
    #pragma unroll
    for (int p = 0; p < 16; p++) {
      int dd = p * 4 + quad;
      Vt[base + (size_t)dd * 2048 + st * 64 + lane] = (unsigned short)t[lane][dd];
    }
    return;
  }
  // ---- norm+rope part ----
  const int w = tid >> 6, d = tid & 63;
  const float qs = q_scale[d], ks = k_scale[d];
  #pragma unroll
  for (int k = 0; k < 4; k++) {
    int task = blockIdx.x * 16 + w * 4 + k;
    const int hid = task % 40;
    const int row = task / 40;            // b*2048 + s
    const int b = row >> 11, s = row & 2047;
    float val, sc;
    if (hid < 32) {
      val = bf2f(QKV[(size_t)row * 3072 + hid * 64 + d]);
      sc = qs;
    } else {
      val = bf2f(QKV[(size_t)row * 3072 + 2048 + (hid - 32) * 64 + d]);
      sc = ks;
    }
    float v2 = val * val;
    #pragma unroll
    for (int off = 32; off; off >>= 1) v2 += __shfl_xor(v2, off);
    float t = val * (1.0f / sqrtf(v2 * (1.0f / 64.0f) + 1e-6f)) * sc;
    float partner = __shfl_xor(t, 32);
    float rot = (d < 32) ? -partner : partner;
    float o = t * cosb[s * 64 + d] + rot * sinb[s * 64 + d];
    if (hid < 32) o *= 0.18033688011112042f;   // fold softmax scale into Q
    unsigned short ob = f2bf(o);
    if (hid < 32) Qn[((size_t)(b * 32 + hid) * 2048 + s) * 64 + d] = ob;
    else          Kn[((size_t)(b * 8 + (hid - 32)) * 2048 + s) * 64 + d] = ob;
  }
}

// ---------------- causal flash attention v12: q-pair blocks ----------------
// v11 + each block owns TWO adjacent 32-row q-tiles (64 q rows/wave) of the
// same head: the staged K/V tile is consumed twice (QK->sm->PV for q-tile A,
// then B, each byte-identical math to v11; B uses a second P half to avoid
// same-addr WAR). K/V staging traffic and barriers HALVED; 64 MFMA per stage.
// Block's causal span ends exactly at tile u (Q0A=64u): mask only at the last
// tile, same formula for both halves. Grid 512 = 2 blocks/CU exactly; LDS
// 67KB -> 2 blocks/CU; launch_bounds(256,2) -> up to 256 VGPR (state ~170,
// no spill headroom issue - the v8 lesson).
__global__ __launch_bounds__(256, 2) void attn_kernel(const unsigned short* __restrict__ Qn,
                                                      const unsigned short* __restrict__ Kn,
                                                      const unsigned short* __restrict__ Vt,
                                                      unsigned short* __restrict__ Outv) {
  __shared__ alignas(16) unsigned short Ksh[2][4096];   // [buf][64 rows x 64 d]
  __shared__ alignas(16) unsigned short Vsh[2][4096];   // [buf][64 rows(d) x 64 kv]
  __shared__ alignas(16) char Psh[4][8704];             // per-wave P buffers (2 halves)

  const int tid = threadIdx.x, w = tid >> 6, lane = tid & 63;
  const int g = lane >> 4, c = lane & 15;
  const int cs = c & 7;
  const int rl = (lane >> 3) & 7;      // staging: row within 1KB chunk
  const int sl = lane & 7;             // staging: 16B slot within row
  const int swz = (sl ^ rl) << 3;      // pre-swizzled source column (elements)
  const int bid = blockIdx.x;                      // [0, 512)
  const int u = 31 - (bid >> 4);                   // longest blocks first
  const int rem = bid & 15;
  const int hg = rem & 7, b = rem >> 3;
  const int h = hg * 4 + w;
  const int Q0 = u * 64;                           // q rows [Q0, Q0+64)
  const unsigned short* Qp = Qn + ((size_t)(b * NHEADS + h) * S_LEN + Q0) * HDIM;
  const unsigned short* Kp = Kn + (size_t)(b * NKV + hg) * S_LEN * HDIM;
  const unsigned short* Vp = Vt + (size_t)(b * NKV + hg) * HDIM * S_LEN;  // [d][s]
  const int ntiles = u + 1;
  char* PA = Psh[w];                   // q-tile A P buffer (32 rows x 128 B, swizzled)
  char* PB = PA + 4352;                // q-tile B P buffer

  // Q as B-operand for both q-tiles: B[k=d][n=q], n = c, k = g*8+j (+t*32)
  bf16x8 bqA[2][2], bqB[2][2];
  #pragma unroll
  for (int iq = 0; iq < 2; iq++)
    #pragma unroll
    for (int t = 0; t < 2; t++) {
      bqA[iq][t] = *(const bf16x8*)(Qp + (iq * 16 + c) * HDIM + t * 32 + g * 8);
      bqB[iq][t] = *(const bf16x8*)(Qp + (32 + iq * 16 + c) * HDIM + t * 32 + g * 8);
    }

  f32x4 OTA[4][2] = {}, OTB[4][2] = {};   // O^T tiles: [dt][iq], row=d, col=q
  float lvA[2] = {0.f, 0.f}, lvB[2] = {0.f, 0.f};

  const int wr0 = w * 16;       // this wave's 16 staging rows

  auto STAGE = [&](int kv0s, int bi) {
    #pragma unroll
    for (int q = 0; q < 2; q++) {
      const int rr = wr0 + q * 8;
      __builtin_amdgcn_global_load_lds(AS1(Kp + (size_t)(kv0s + rr + rl) * 64 + swz),
                                       AS3(&Ksh[bi][rr * 64]), 16, 0, 0);
      __builtin_amdgcn_global_load_lds(AS1(Vp + (size_t)(rr + rl) * 2048 + kv0s + swz),
                                       AS3(&Vsh[bi][rr * 64]), 16, 0, 0);
    }
  };

  STAGE(0, 0);
  __syncthreads();

  for (int ti = 0; ti < ntiles; ti++) {
    const int kv0 = ti * 64;
    const int cur = ti & 1;
    if (ti + 1 < ntiles) STAGE(kv0 + 64, cur ^ 1);

    const unsigned short* Kb = Ksh[cur];
    const unsigned short* Vb = Vsh[cur];

    // ======== q-tile A, then q-tile B: verified v11 sequence each ========
    #pragma unroll
    for (int qtile = 0; qtile < 2; qtile++) {
      const int qbase = Q0 + qtile * 32;
      char* Pw = qtile ? PB : PA;
      // QK + softmax in two jt-pairs (Sx live = 16 regs)
      #pragma unroll
      for (int jb = 0; jb < 2; jb++) {
        bf16x8 akx[2][2];
        #pragma unroll
        for (int jt = 0; jt < 2; jt++)
          #pragma unroll
          for (int t = 0; t < 2; t++)
            akx[jt][t] = *(const bf16x8*)(Kb + ((jb * 2 + jt) * 16 + c) * 64 +
                                          (((t * 4 + g) ^ cs) << 3));
        f32x4 Sx[2][2] = {};
        __builtin_amdgcn_s_setprio(1);
        #pragma unroll
        for (int t = 0; t < 2; t++)
          #pragma unroll
          for (int jt = 0; jt < 2; jt++)
            #pragma unroll
            for (int iq = 0; iq < 2; iq++)
              Sx[jt][iq] = MFMA_BF16(akx[jt][t], qtile ? bqB[iq][t] : bqA[iq][t],
                                     Sx[jt][iq], 0, 0, 0);
        __builtin_amdgcn_s_setprio(0);

        if (ti == ntiles - 1) {   // only the final tile crosses the diagonal
          #pragma unroll
          for (int jt = 0; jt < 2; jt++)
            #pragma unroll
            for (int iq = 0; iq < 2; iq++)
              #pragma unroll
              for (int r = 0; r < 4; r++) {
                int kv = kv0 + (jb * 2 + jt) * 16 + g * 4 + r;
                int q  = qbase + iq * 16 + c;
                if (kv > q) Sx[jt][iq][r] = -1e30f;
              }
        }

        // fixed-max softmax: p = exp2(s); accumulate l; pack P -> LDS (swizzled)
        #pragma unroll
        for (int jt = 0; jt < 2; jt++)
          #pragma unroll
          for (int iq = 0; iq < 2; iq++) {
            f32x4 p;
            #pragma unroll
            for (int r = 0; r < 4; r++) p[r] = EXP2F(Sx[jt][iq][r]);
            float ps = (p[0] + p[1]) + (p[2] + p[3]);
            if (qtile) lvB[iq] += ps; else lvA[iq] += ps;
            uint32_t u0 = __float_as_uint(p[0]) + 0x8000u;
            uint32_t u1 = __float_as_uint(p[1]) + 0x8000u;
            uint32_t u2 = __float_as_uint(p[2]) + 0x8000u;
            uint32_t u3 = __float_as_uint(p[3]) + 0x8000u;
            uint32_t lo = __builtin_amdgcn_perm(u1, u0, 0x07060302u);
            uint32_t hi = __builtin_amdgcn_perm(u3, u2, 0x07060302u);
            int row = iq * 16 + c;                       // local q
            int bytecol = (jb * 2 + jt) * 32 + g * 8;    // kv-contiguous bytes
            uint32_t off = row * 128 + (((bytecol >> 4) ^ (row & 7)) << 4) + (bytecol & 15);
            *(uint2*)(Pw + off) = make_uint2(lo, hi);
          }
      }

      __builtin_amdgcn_s_waitcnt(0xC07F);        // lgkmcnt(0): P writes visible

      // PV per t-half: V from LDS, P as B-operand B[k=kv][n=q]
      #pragma unroll
      for (int t = 0; t < 2; t++) {
        bf16x8 avt[4];
        #pragma unroll
        for (int dt = 0; dt < 4; dt++)
          avt[dt] = *(const bf16x8*)(Vb + (dt * 16 + c) * 64 + (((t * 4 + g) ^ cs) << 3));
        bf16x8 bpt[2];
        #pragma unroll
        for (int iq = 0; iq < 2; iq++) {
          int row = iq * 16 + c;
          int bytecol = t * 64 + g * 16;
          uint32_t off = row * 128 + (((bytecol >> 4) ^ (row & 7)) << 4);
          bpt[iq] = *(const bf16x8*)(Pw + off);
        }
        __builtin_amdgcn_s_setprio(1);
        #pragma unroll
        for (int dt = 0; dt < 4; dt++)
          #pragma unroll
          for (int iq = 0; iq < 2; iq++) {
            if (qtile) OTB[dt][iq] = MFMA_BF16(avt[dt], bpt[iq], OTB[dt][iq], 0, 0, 0);
            else       OTA[dt][iq] = MFMA_BF16(avt[dt], bpt[iq], OTA[dt][iq], 0, 0, 0);
          }
        __builtin_amdgcn_s_setprio(0);
      }
    }

    if (ti + 1 < ntiles) __syncthreads();      // stage(i+1) drained + all reads done
  }

  // l: per-lane partial covers kv rows {jt*16+g*4+r}; butterfly over g
  float invA[2], invB[2];
  #pragma unroll
  for (int iq = 0; iq < 2; iq++) {
    float sA = lvA[iq];
    sA += __shfl_xor(sA, 16);
    sA += __shfl_xor(sA, 32);
    invA[iq] = 1.0f / sA;
    float sB = lvB[iq];
    sB += __shfl_xor(sB, 16);
    sB += __shfl_xor(sB, 32);
    invB[iq] = 1.0f / sB;
  }

  // write O for both q-tiles: lane holds d = dt*16+g*4+{0..3}, q = qbase+iq*16+c
  #pragma unroll
  for (int qtile = 0; qtile < 2; qtile++) {
    #pragma unroll
    for (int iq = 0; iq < 2; iq++) {
      const int q = Q0 + qtile * 32 + iq * 16 + c;
      const float iv = qtile ? invB[iq] : invA[iq];
      unsigned short* orow = Outv + (size_t)(b * S_LEN + q) * (NHEADS * HDIM) + h * HDIM;
      #pragma unroll
      for (int dt = 0; dt < 4; dt++) {
        const f32x4& o = qtile ? OTB[dt][iq] : OTA[dt][iq];
        uint32_t u0 = __float_as_uint(o[0] * iv) + 0x8000u;
        uint32_t u1 = __float_as_uint(o[1] * iv) + 0x8000u;
        uint32_t u2 = __float_as_uint(o[2] * iv) + 0x8000u;
        uint32_t u3 = __float_as_uint(o[3] * iv) + 0x8000u;
        uint32_t lo = __builtin_amdgcn_perm(u1, u0, 0x07060302u);
        uint32_t hi = __builtin_amdgcn_perm(u3, u2, 0x07060302u);
        *(uint2*)(orow + dt * 16 + g * 4) = make_uint2(lo, hi);
      }
    }
  }
}

extern "C" void kernel_launch(void* const* d_in, const int* in_sizes, int n_in,
                              void* d_out, int out_size, void* d_ws, size_t ws_size,
                              hipStream_t stream) {
  const float* x       = (const float*)d_in[0];
  // d_in[1] = mask (causal, implemented analytically)
  const float* cosb    = (const float*)d_in[2];
  const float* sinb    = (const float*)d_in[3];
  const float* Wq      = (const float*)d_in[4];
  const float* Wk      = (const float*)d_in[5];
  const float* Wv      = (const float*)d_in[6];
  const float* Wo      = (const float*)d_in[7];
  const float* q_scale = (const float*)d_in[8];
  const float* k_scale = (const float*)d_in[9];

  char* ws = (char*)d_ws;
  unsigned short* xb   = (unsigned short*)(ws);                       // 16 MiB: x bf16 [4096][2048]
  unsigned short* wcat = (unsigned short*)(ws + (16ull << 20));       // 12 MiB: Wt [3072][2048]
  unsigned short* wo_t = (unsigned short*)(ws + (28ull << 20));       //  8 MiB: Wo_t [2048][2048]
  unsigned short* qkv  = (unsigned short*)(ws + (36ull << 20));       // 24 MiB: QKV bf16 [4096][3072]
  unsigned short* qn   = (unsigned short*)(ws + (84ull << 20));       // 16 MiB: Q bf16 [b][h][s][d]
  unsigned short* kn   = (unsigned short*)(ws + (100ull << 20));      //  4 MiB: K bf16 [b][kv][s][d]
  unsigned short* vt   = (unsigned short*)(ws + (104ull << 20));      //  4 MiB: V^T bf16 [b][kv][d][s]
  unsigned short* vec  = (unsigned short*)(ws + (36ull << 20));       // alias qkv (dead after v_transpose)

  prep_kernel<<<18432, 256, 0, stream>>>(x, Wq, Wk, Wv, Wo, xb, wcat, wo_t);
  gemm_nt<unsigned short><<<768, 256, 0, stream>>>(xb, wcat, qkv, 4096, 3072, 2048, 24);
  norm_rope_vt<<<10752, 256, 0, stream>>>(qkv, cosb, sinb, q_scale, k_scale, qn, kn, vt);
  attn_kernel<<<512, 256, 0, stream>>>(qn, kn, vt, vec);
  gemm_nt<float><<<512, 256, 0, stream>>>(vec, wo_t, (float*)d_out, 4096, 2048, 2048, 16);
}

// Round 11
// 301.573 us; speedup vs baseline: 1.1126x; 1.1126x over previous
//
#include <hip/hip_runtime.h>
#include <hip/hip_bf16.h>
#include <stdint.h>

#define S_LEN   2048
#define DIN     2048
#define NHEADS  32
#define HDIM    64
#define NKV     8

typedef __bf16 bf16x8 __attribute__((ext_vector_type(8)));
typedef float  f32x4  __attribute__((ext_vector_type(4)));

#define AS1(p) ((__attribute__((address_space(1))) void*)(void*)(p))
#define AS3(p) ((__attribute__((address_space(3))) void*)(p))
#define MFMA_BF16 __builtin_amdgcn_mfma_f32_16x16x32_bf16

#if __has_builtin(__builtin_amdgcn_exp2f)
#define EXP2F(x) __builtin_amdgcn_exp2f(x)
#else
#define EXP2F(x) exp2f(x)
#endif

static __device__ __forceinline__ unsigned short f2bf(float f) {
  unsigned int x = __float_as_uint(f);
  return (unsigned short)((x + 0x7fffu + ((x >> 16) & 1u)) >> 16);
}
static __device__ __forceinline__ float bf2f(unsigned short u) {
  return __uint_as_float((unsigned int)u << 16);
}

// ---------------- fused prep: cast x + transpose Wqkv + transpose Wo ----------------
__global__ __launch_bounds__(256) void prep_kernel(const float* __restrict__ x,
                                                   const float* __restrict__ Wq,
                                                   const float* __restrict__ Wk,
                                                   const float* __restrict__ Wv,
                                                   const float* __restrict__ Wo,
                                                   unsigned short* __restrict__ xb,
                                                   unsigned short* __restrict__ wcat,
                                                   unsigned short* __restrict__ wo_t) {
  const int bid = blockIdx.x;
  if (bid < 8192) {                      // cast x: 8192*256 == 2097152 float4s exactly
    int i = bid * 256 + threadIdx.x;
    float4 f = ((const float4*)x)[i];
    ((ushort4*)xb)[i] = make_ushort4(f2bf(f.x), f2bf(f.y), f2bf(f.z), f2bf(f.w));
    return;
  }
  __shared__ float t[32][33];
  const int tx = threadIdx.x & 31, ty = threadIdx.x >> 5;
  const float* src; unsigned short* dst; int n0, k0, col0, srcN, dstK;
  if (bid < 14336) {                     // Wqkv transpose: grid (96,64)
    int b2 = bid - 8192;
    n0 = (b2 % 96) * 32; k0 = (b2 / 96) * 32;
    if (n0 < 2048)      { src = Wq; col0 = n0;        srcN = 2048; }
    else if (n0 < 2560) { src = Wk; col0 = n0 - 2048; srcN = 512; }
    else                { src = Wv; col0 = n0 - 2560; srcN = 512; }
    dst = wcat; dstK = 2048;
  } else {                               // Wo transpose: grid (64,64)
    int b3 = bid - 14336;
    n0 = (b3 % 64) * 32; k0 = (b3 / 64) * 32;
    src = Wo; col0 = n0; srcN = 2048; dst = wo_t; dstK = 2048;
  }
  #pragma unroll
  for (int j = 0; j < 32; j += 8)
    t[ty + j][tx] = src[(size_t)(k0 + ty + j) * srcN + col0 + tx];
  __syncthreads();
  #pragma unroll
  for (int j = 0; j < 32; j += 8)
    dst[(size_t)(n0 + ty + j) * dstK + k0 + tx] = f2bf(t[tx][ty + j]);
}

// ---------------- bf16 NT GEMM, BK=64 + XCD-aware block swizzle ----------------
// Round-9 verified BK=64 structure + T1 bijective XCD remap (kept from round 10;
// this round's single variable vs the 315us round-9 baseline is this swizzle —
// attn is reverted to v11 verbatim).
template <typename OutT>
__global__ __launch_bounds__(256) void gemm_nt(const unsigned short* __restrict__ A,
                                               const unsigned short* __restrict__ Bt,
                                               OutT* __restrict__ C,
                                               int M, int N, int K, int nxb) {
  __shared__ alignas(16) unsigned short As[2][4096];   // [half][128 rows x 32 k]
  __shared__ alignas(16) unsigned short Bs[2][4096];
  const int tid = threadIdx.x;
  const int wave = tid >> 6, lane = tid & 63;
  const int g = lane >> 4, c = lane & 15;
  const int id = blockIdx.x;
  const int cpx = gridDim.x >> 3;                      // blocks per XCD
  const int swb = (id & 7) * cpx + (id >> 3);          // bijective XCD chunking
  const int m0 = (swb / nxb) * 128, n0 = (swb % nxb) * 128;
  const int wm = (wave & 1) * 64, wn = (wave >> 1) * 64;

  f32x4 acc[4][4] = {};

  const int ch0 = wave * 2;
  const int p0 = ch0 * 64 + lane, p1 = p0 + 64;
  const int r0 = p0 >> 2, gc0 = ((p0 & 3) ^ ((r0 >> 1) & 3)) * 8;
  const int r1 = p1 >> 2, gc1 = ((p1 & 3) ^ ((r1 >> 1) & 3)) * 8;
  const unsigned short* a0 = A + (size_t)(m0 + r0) * K + gc0;
  const unsigned short* a1 = A + (size_t)(m0 + r1) * K + gc1;
  const unsigned short* b0 = Bt + (size_t)(n0 + r0) * K + gc0;
  const unsigned short* b1 = Bt + (size_t)(n0 + r1) * K + gc1;
  const int fswz = (c >> 1) & 3;   // f(row) for consumer rows (wm,i*16 are mult of 16)

  for (int k0 = 0; k0 < K; k0 += 64) {
    __syncthreads();
    __builtin_amdgcn_global_load_lds(AS1(a0 + k0), AS3(&As[0][ch0 * 512]), 16, 0, 0);
    __builtin_amdgcn_global_load_lds(AS1(a1 + k0), AS3(&As[0][ch0 * 512 + 512]), 16, 0, 0);
    __builtin_amdgcn_global_load_lds(AS1(b0 + k0), AS3(&Bs[0][ch0 * 512]), 16, 0, 0);
    __builtin_amdgcn_global_load_lds(AS1(b1 + k0), AS3(&Bs[0][ch0 * 512 + 512]), 16, 0, 0);
    __builtin_amdgcn_global_load_lds(AS1(a0 + k0 + 32), AS3(&As[1][ch0 * 512]), 16, 0, 0);
    __builtin_amdgcn_global_load_lds(AS1(a1 + k0 + 32), AS3(&As[1][ch0 * 512 + 512]), 16, 0, 0);
    __builtin_amdgcn_global_load_lds(AS1(b0 + k0 + 32), AS3(&Bs[1][ch0 * 512]), 16, 0, 0);
    __builtin_amdgcn_global_load_lds(AS1(b1 + k0 + 32), AS3(&Bs[1][ch0 * 512 + 512]), 16, 0, 0);
    __builtin_amdgcn_s_waitcnt(0);
    __syncthreads();

    #pragma unroll
    for (int h = 0; h < 2; h++) {
      bf16x8 af[4], bfr[4];
      #pragma unroll
      for (int i = 0; i < 4; i++)
        af[i] = *(const bf16x8*)(&As[h][(wm + i * 16 + c) * 32 + (g ^ fswz) * 8]);
      #pragma unroll
      for (int j = 0; j < 4; j++)
        bfr[j] = *(const bf16x8*)(&Bs[h][(wn + j * 16 + c) * 32 + (g ^ fswz) * 8]);
      #pragma unroll
      for (int i = 0; i < 4; i++)
        #pragma unroll
        for (int j = 0; j < 4; j++)
          acc[i][j] = MFMA_BF16(af[i], bfr[j], acc[i][j], 0, 0, 0);
    }
  }

  #pragma unroll
  for (int i = 0; i < 4; i++)
    #pragma unroll
    for (int j = 0; j < 4; j++)
      #pragma unroll
      for (int r = 0; r < 4; r++) {
        size_t idx = (size_t)(m0 + wm + i * 16 + g * 4 + r) * N + n0 + wn + j * 16 + c;
        if constexpr (sizeof(OutT) == 2) C[idx] = f2bf(acc[i][j][r]);
        else                             C[idx] = acc[i][j][r];
      }
}

// ---------------- fused norm_rope + v_transpose ----------------
__global__ __launch_bounds__(256) void norm_rope_vt(const unsigned short* __restrict__ QKV,
                                                    const float* __restrict__ cosb,
                                                    const float* __restrict__ sinb,
                                                    const float* __restrict__ q_scale,
                                                    const float* __restrict__ k_scale,
                                                    unsigned short* __restrict__ Qn,
                                                    unsigned short* __restrict__ Kn,
                                                    unsigned short* __restrict__ Vt) {
  const int tid = threadIdx.x;
  if (blockIdx.x >= 10240) {             // ---- V transpose part ----
    __shared__ unsigned int t[64][65];
    int bid = blockIdx.x - 10240;
    const int st = bid & 31, kv = (bid >> 5) & 7, b = bid >> 8;
    const int lane = tid & 63, quad = tid >> 6;
    #pragma unroll
    for (int p = 0; p < 16; p++) {
      int sl = p * 4 + quad;
      t[sl][lane] = QKV[(size_t)(b * 2048 + st * 64 + sl) * 3072 + 2560 + kv * 64 + lane];
    }
    __syncthreads();
    size_t base = (size_t)(b * 8 + kv) * 64 * 2048;
    #pragma unroll
    for (int p = 0; p < 16; p++) {
      int dd = p * 4 + quad;
      Vt[base + (size_t)dd * 2048 + st * 64 + lane] = (unsigned short)t[lane][dd];
    }
    return;
  }
  // ---- norm+rope part ----
  const int w = tid >> 6, d = tid & 63;
  const float qs = q_scale[d], ks = k_scale[d];
  #pragma unroll
  for (int k = 0; k < 4; k++) {
    int task = blockIdx.x * 16 + w * 4 + k;
    const int hid = task % 40;
    const int row = task / 40;            // b*2048 + s
    const int b = row >> 11, s = row & 2047;
    float val, sc;
    if (hid < 32) {
      val = bf2f(QKV[(size_t)row * 3072 + hid * 64 + d]);
      sc = qs;
    } else {
      val = bf2f(QKV[(size_t)row * 3072 + 2048 + (hid - 32) * 64 + d]);
      sc = ks;
    }
    float v2 = val * val;
    #pragma unroll
    for (int off = 32; off; off >>= 1) v2 += __shfl_xor(v2, off);
    float t = val * (1.0f / sqrtf(v2 * (1.0f / 64.0f) + 1e-6f)) * sc;
    float partner = __shfl_xor(t, 32);
    float rot = (d < 32) ? -partner : partner;
    float o = t * cosb[s * 64 + d] + rot * sinb[s * 64 + d];
    if (hid < 32) o *= 0.18033688011112042f;   // fold softmax scale into Q
    unsigned short ob = f2bf(o);
    if (hid < 32) Qn[((size_t)(b * 32 + hid) * 2048 + s) * 64 + d] = ob;
    else          Kn[((size_t)(b * 8 + (hid - 32)) * 2048 + s) * 64 + d] = ob;
  }
}

// ---------------- causal flash attention v11 (reverted to round-9 verbatim) ----------
// v12's q-pair experiment regressed (75 vs ~60us: occupancy 19->12.5%, doubled
// serial chain between lgkm drains). Reverted; v11 is the best measured attn.
__global__ __launch_bounds__(256, 3) void attn_kernel(const unsigned short* __restrict__ Qn,
                                                      const unsigned short* __restrict__ Kn,
                                                      const unsigned short* __restrict__ Vt,
                                                      unsigned short* __restrict__ Outv) {
  __shared__ alignas(16) unsigned short Ksh[2][4096];   // [buf][64 rows x 64 d]
  __shared__ alignas(16) unsigned short Vsh[2][4096];   // [buf][64 rows(d) x 64 kv]
  __shared__ alignas(16) char Psh[4][4352];             // per-wave P buffers

  const int tid = threadIdx.x, w = tid >> 6, lane = tid & 63;
  const int g = lane >> 4, c = lane & 15;
  const int cs = c & 7;
  const int rl = (lane >> 3) & 7;      // staging: row within 1KB chunk
  const int sl = lane & 7;             // staging: 16B slot within row
  const int swz = (sl ^ rl) << 3;      // pre-swizzled source column (elements)
  const int bid = blockIdx.x;                      // [0, 1024)
  const int qt = 63 - (bid >> 4);                  // longest blocks first
  const int rem = bid & 15;
  const int hg = rem & 7, b = rem >> 3;
  const int h = hg * 4 + w;
  const int Q0 = qt * 32;
  const unsigned short* Qp = Qn + ((size_t)(b * NHEADS + h) * S_LEN + Q0) * HDIM;
  const unsigned short* Kp = Kn + (size_t)(b * NKV + hg) * S_LEN * HDIM;
  const unsigned short* Vp = Vt + (size_t)(b * NKV + hg) * HDIM * S_LEN;  // [d][s]
  const int ntiles = (qt >> 1) + 1;
  char* PwB = Psh[w];                  // 32 rows x 128 B, swizzled

  // Q as B-operand: B[k=d][n=q], n = c, k = g*8+j (+t*32)
  bf16x8 bq[2][2];
  #pragma unroll
  for (int iq = 0; iq < 2; iq++)
    #pragma unroll
    for (int t = 0; t < 2; t++)
      bq[iq][t] = *(const bf16x8*)(Qp + (iq * 16 + c) * HDIM + t * 32 + g * 8);

  f32x4 OT[4][2] = {};          // O^T tiles: [dt][iq], row=d, col=q
  float lv[2] = {0.f, 0.f};     // per-lane l partials

  const int wr0 = w * 16;       // this wave's 16 staging rows

  // stage K rows [kv0+wr0, +16) and V^T rows [wr0, +16) of the kv window
  auto STAGE = [&](int kv0s, int bi) {
    #pragma unroll
    for (int q = 0; q < 2; q++) {
      const int rr = wr0 + q * 8;
      __builtin_amdgcn_global_load_lds(AS1(Kp + (size_t)(kv0s + rr + rl) * 64 + swz),
                                       AS3(&Ksh[bi][rr * 64]), 16, 0, 0);
      __builtin_amdgcn_global_load_lds(AS1(Vp + (size_t)(rr + rl) * 2048 + kv0s + swz),
                                       AS3(&Vsh[bi][rr * 64]), 16, 0, 0);
    }
  };

  STAGE(0, 0);
  __syncthreads();

  for (int ti = 0; ti < ntiles; ti++) {
    const int kv0 = ti * 64;
    const int cur = ti & 1;
    if (ti + 1 < ntiles) STAGE(kv0 + 64, cur ^ 1);

    const unsigned short* Kb = Ksh[cur];
    const unsigned short* Vb = Vsh[cur];

    // QK + softmax in two jt-pairs (Sx live = 16 regs)
    #pragma unroll
    for (int jb = 0; jb < 2; jb++) {
      bf16x8 akx[2][2];
      #pragma unroll
      for (int jt = 0; jt < 2; jt++)
        #pragma unroll
        for (int t = 0; t < 2; t++)
          akx[jt][t] = *(const bf16x8*)(Kb + ((jb * 2 + jt) * 16 + c) * 64 +
                                        (((t * 4 + g) ^ cs) << 3));
      f32x4 Sx[2][2] = {};
      __builtin_amdgcn_s_setprio(1);
      #pragma unroll
      for (int t = 0; t < 2; t++)
        #pragma unroll
        for (int jt = 0; jt < 2; jt++)
          #pragma unroll
          for (int iq = 0; iq < 2; iq++)
            Sx[jt][iq] = MFMA_BF16(akx[jt][t], bq[iq][t], Sx[jt][iq], 0, 0, 0);
      __builtin_amdgcn_s_setprio(0);

      if (ti == ntiles - 1) {   // only the final tile crosses the diagonal
        #pragma unroll
        for (int jt = 0; jt < 2; jt++)
          #pragma unroll
          for (int iq = 0; iq < 2; iq++)
            #pragma unroll
            for (int r = 0; r < 4; r++) {
              int kv = kv0 + (jb * 2 + jt) * 16 + g * 4 + r;
              int q  = Q0 + iq * 16 + c;
              if (kv > q) Sx[jt][iq][r] = -1e30f;
            }
      }

      // fixed-max softmax: p = exp2(s); accumulate l; pack P -> LDS (swizzled)
      #pragma unroll
      for (int jt = 0; jt < 2; jt++)
        #pragma unroll
        for (int iq = 0; iq < 2; iq++) {
          f32x4 p;
          #pragma unroll
          for (int r = 0; r < 4; r++) p[r] = EXP2F(Sx[jt][iq][r]);
          lv[iq] += (p[0] + p[1]) + (p[2] + p[3]);
          uint32_t u0 = __float_as_uint(p[0]) + 0x8000u;
          uint32_t u1 = __float_as_uint(p[1]) + 0x8000u;
          uint32_t u2 = __float_as_uint(p[2]) + 0x8000u;
          uint32_t u3 = __float_as_uint(p[3]) + 0x8000u;
          uint32_t lo = __builtin_amdgcn_perm(u1, u0, 0x07060302u);
          uint32_t hi = __builtin_amdgcn_perm(u3, u2, 0x07060302u);
          int row = iq * 16 + c;                       // local q
          int bytecol = (jb * 2 + jt) * 32 + g * 8;    // kv-contiguous bytes
          uint32_t off = row * 128 + (((bytecol >> 4) ^ (row & 7)) << 4) + (bytecol & 15);
          *(uint2*)(PwB + off) = make_uint2(lo, hi);
        }
    }

    __builtin_amdgcn_s_waitcnt(0xC07F);        // lgkmcnt(0): P writes visible

    // PV per t-half: V from LDS, P as B-operand B[k=kv][n=q]
    #pragma unroll
    for (int t = 0; t < 2; t++) {
      bf16x8 avt[4];
      #pragma unroll
      for (int dt = 0; dt < 4; dt++)
        avt[dt] = *(const bf16x8*)(Vb + (dt * 16 + c) * 64 + (((t * 4 + g) ^ cs) << 3));
      bf16x8 bpt[2];
      #pragma unroll
      for (int iq = 0; iq < 2; iq++) {
        int row = iq * 16 + c;
        int bytecol = t * 64 + g * 16;
        uint32_t off = row * 128 + (((bytecol >> 4) ^ (row & 7)) << 4);
        bpt[iq] = *(const bf16x8*)(PwB + off);
      }
      __builtin_amdgcn_s_setprio(1);
      #pragma unroll
      for (int dt = 0; dt < 4; dt++)
        #pragma unroll
        for (int iq = 0; iq < 2; iq++)
          OT[dt][iq] = MFMA_BF16(avt[dt], bpt[iq], OT[dt][iq], 0, 0, 0);
      __builtin_amdgcn_s_setprio(0);
    }

    if (ti + 1 < ntiles) __syncthreads();      // stage(i+1) drained + all reads done
  }

  // l: per-lane partial covers kv rows {jt*16+g*4+r}; butterfly over g
  float inv[2];
  #pragma unroll
  for (int iq = 0; iq < 2; iq++) {
    float s = lv[iq];
    s += __shfl_xor(s, 16);
    s += __shfl_xor(s, 32);
    inv[iq] = 1.0f / s;
  }

  // write O: lane holds d = dt*16+g*4+{0..3}, q = Q0+iq*16+c -> 8B stores
  #pragma unroll
  for (int iq = 0; iq < 2; iq++) {
    const int q = Q0 + iq * 16 + c;
    unsigned short* orow = Outv + (size_t)(b * S_LEN + q) * (NHEADS * HDIM) + h * HDIM;
    #pragma unroll
    for (int dt = 0; dt < 4; dt++) {
      uint32_t u0 = __float_as_uint(OT[dt][iq][0] * inv[iq]) + 0x8000u;
      uint32_t u1 = __float_as_uint(OT[dt][iq][1] * inv[iq]) + 0x8000u;
      uint32_t u2 = __float_as_uint(OT[dt][iq][2] * inv[iq]) + 0x8000u;
      uint32_t u3 = __float_as_uint(OT[dt][iq][3] * inv[iq]) + 0x8000u;
      uint32_t lo = __builtin_amdgcn_perm(u1, u0, 0x07060302u);
      uint32_t hi = __builtin_amdgcn_perm(u3, u2, 0x07060302u);
      *(uint2*)(orow + dt * 16 + g * 4) = make_uint2(lo, hi);
    }
  }
}

extern "C" void kernel_launch(void* const* d_in, const int* in_sizes, int n_in,
                              void* d_out, int out_size, void* d_ws, size_t ws_size,
                              hipStream_t stream) {
  const float* x       = (const float*)d_in[0];
  // d_in[1] = mask (causal, implemented analytically)
  const float* cosb    = (const float*)d_in[2];
  const float* sinb    = (const float*)d_in[3];
  const float* Wq      = (const float*)d_in[4];
  const float* Wk      = (const float*)d_in[5];
  const float* Wv      = (const float*)d_in[6];
  const float* Wo      = (const float*)d_in[7];
  const float* q_scale = (const float*)d_in[8];
  const float* k_scale = (const float*)d_in[9];

  char* ws = (char*)d_ws;
  unsigned short* xb   = (unsigned short*)(ws);                       // 16 MiB: x bf16 [4096][2048]
  unsigned short* wcat = (unsigned short*)(ws + (16ull << 20));       // 12 MiB: Wt [3072][2048]
  unsigned short* wo_t = (unsigned short*)(ws + (28ull << 20));       //  8 MiB: Wo_t [2048][2048]
  unsigned short* qkv  = (unsigned short*)(ws + (36ull << 20));       // 24 MiB: QKV bf16 [4096][3072]
  unsigned short* qn   = (unsigned short*)(ws + (84ull << 20));       // 16 MiB: Q bf16 [b][h][s][d]
  unsigned short* kn   = (unsigned short*)(ws + (100ull << 20));      //  4 MiB: K bf16 [b][kv][s][d]
  unsigned short* vt   = (unsigned short*)(ws + (104ull << 20));      //  4 MiB: V^T bf16 [b][kv][d][s]
  unsigned short* vec  = (unsigned short*)(ws + (36ull << 20));       // alias qkv (dead after v_transpose)

  prep_kernel<<<18432, 256, 0, stream>>>(x, Wq, Wk, Wv, Wo, xb, wcat, wo_t);
  gemm_nt<unsigned short><<<768, 256, 0, stream>>>(xb, wcat, qkv, 4096, 3072, 2048, 24);
  norm_rope_vt<<<10752, 256, 0, stream>>>(qkv, cosb, sinb, q_scale, k_scale, qn, kn, vt);
  attn_kernel<<<1024, 256, 0, stream>>>(qn, kn, vt, vec);
  gemm_nt<float><<<512, 256, 0, stream>>>(vec, wo_t, (float*)d_out, 4096, 2048, 2048, 16);
}